// Round 11
// baseline (300.501 us; speedup 1.0000x reference)
//
#include <hip/hip_runtime.h>
#include <stdint.h>

#define HID 1024
#define NSEQ 1024
#define KREL 1024
#define NHEAD 16
#define DHEAD 64

typedef __attribute__((ext_vector_type(8))) short bhalf8;
typedef __attribute__((ext_vector_type(4))) float floatx4;

__device__ inline uint16_t f2bf(float f) {
  union { float f; uint32_t u; } c; c.f = f;
  uint32_t u = c.u;
  return (uint16_t)((u + 0x7fffu + ((u >> 16) & 1u)) >> 16);
}
__device__ inline uint32_t pkbf(float a, float b) {
  union { float f; uint32_t u; } x, y; x.f = a; y.f = b;
#if __has_builtin(__builtin_amdgcn_perm)
  return __builtin_amdgcn_perm(x.u + 0x8000u, y.u + 0x8000u, 0x03020706u);
#else
  return ((x.u + 0x8000u) >> 16) | ((y.u + 0x8000u) & 0xffff0000u);
#endif
}

// ---------------- fused fp32 -> bf16 casts (8 segments) ----------------
struct Cast8 {
  const float* src[8];
  uint16_t* dst[8];
  int n[8];
};
__global__ __launch_bounds__(256) void cast8_kernel(Cast8 c) {
  int seg = blockIdx.y;
  int n = c.n[seg];
  const float* s = c.src[seg];
  uint16_t* d = c.dst[seg];
  for (int idx = (blockIdx.x * 256 + threadIdx.x) * 4; idx < n; idx += 1024 * 256 * 4) {
    float4 v = *(const float4*)(s + idx);
    ushort4 o;
    o.x = f2bf(v.x); o.y = f2bf(v.y); o.z = f2bf(v.z); o.w = f2bf(v.w);
    *(ushort4*)(d + idx) = o;
  }
}

// ---------------- unified projection GEMM (bf16 in): 128x128 tile, BK=32, sync dbuf ----------------
// (R7/R9/R10-measured best.) z==2 (V) writes transposed Vt[d][i].
struct ProjArgs {
  const uint16_t* A[5];
  const uint16_t* W[5];
  const float* bias[5];
  uint16_t* C[5];
  int trans[5];
};
__global__ __launch_bounds__(256) void proj_gemm(ProjArgs pa) {
  __shared__ uint16_t a_s[2][128 * 40];
  __shared__ uint16_t b_s[2][128 * 40];
  int bidx = blockIdx.x;
  int xcd = bidx & 7, idx = bidx >> 3;
  int g = xcd * 7 + (idx >> 3);
  int nt = idx & 7;
  int z, mt;
  if (g < 24) { z = g >> 3; mt = g & 7; }
  else { int g2 = g - 24; z = 3 + (g2 >> 4); mt = g2 & 15; }
  const uint16_t* A = pa.A[z];
  const uint16_t* W = pa.W[z];
  int i0 = mt * 128, n0 = nt * 128;

  int t = threadIdx.x;
  int lane = t & 63, w = t >> 6;
  int fm = lane & 15, kq = lane >> 4;
  int wm = (w >> 1) * 64, wn = (w & 1) * 64;

  int ra = t >> 1, ca = (t & 1) * 16;
  const uint16_t* Ap = A + (size_t)(i0 + ra) * HID + ca;
  const uint16_t* Wp = W + (size_t)(n0 + ra) * HID + ca;

  floatx4 acc[4][4] = {};

  uint4 ua0 = *(const uint4*)(Ap);
  uint4 ua1 = *(const uint4*)(Ap + 8);
  uint4 ub0 = *(const uint4*)(Wp);
  uint4 ub1 = *(const uint4*)(Wp + 8);
  *(uint4*)(&a_s[0][ra * 40 + ca]) = ua0;
  *(uint4*)(&a_s[0][ra * 40 + ca + 8]) = ua1;
  *(uint4*)(&b_s[0][ra * 40 + ca]) = ub0;
  *(uint4*)(&b_s[0][ra * 40 + ca + 8]) = ub1;

  for (int kt = 0; kt < 32; ++kt) {
    __syncthreads();
    int cur = kt & 1;
    if (kt < 31) {
      int ko = (kt + 1) * 32;
      ua0 = *(const uint4*)(Ap + ko);
      ua1 = *(const uint4*)(Ap + ko + 8);
      ub0 = *(const uint4*)(Wp + ko);
      ub1 = *(const uint4*)(Wp + ko + 8);
    }
    const uint16_t* as = &a_s[cur][0];
    const uint16_t* bs = &b_s[cur][0];
    bhalf8 af[4], bf[4];
#pragma unroll
    for (int m2 = 0; m2 < 4; ++m2)
      af[m2] = *(bhalf8*)(as + (wm + m2 * 16 + fm) * 40 + kq * 8);
#pragma unroll
    for (int n2 = 0; n2 < 4; ++n2)
      bf[n2] = *(bhalf8*)(bs + (wn + n2 * 16 + fm) * 40 + kq * 8);
#pragma unroll
    for (int m2 = 0; m2 < 4; ++m2)
#pragma unroll
      for (int n2 = 0; n2 < 4; ++n2)
        acc[m2][n2] = __builtin_amdgcn_mfma_f32_16x16x32_bf16(af[m2], bf[n2], acc[m2][n2], 0, 0, 0);
    if (kt < 31) {
      int nxt = cur ^ 1;
      *(uint4*)(&a_s[nxt][ra * 40 + ca]) = ua0;
      *(uint4*)(&a_s[nxt][ra * 40 + ca + 8]) = ua1;
      *(uint4*)(&b_s[nxt][ra * 40 + ca]) = ub0;
      *(uint4*)(&b_s[nxt][ra * 40 + ca + 8]) = ub1;
    }
  }

  const float* bias = pa.bias[z];
  uint16_t* C = pa.C[z];
  int tr = pa.trans[z];
#pragma unroll
  for (int m2 = 0; m2 < 4; ++m2) {
    int rowb = i0 + wm + m2 * 16 + kq * 4;
#pragma unroll
    for (int n2 = 0; n2 < 4; ++n2) {
      int col = n0 + wn + n2 * 16 + fm;
      float bv = bias[col];
      floatx4 v = acc[m2][n2];
      if (tr) {
        uint2 p = { pkbf(v[0] + bv, v[1] + bv), pkbf(v[2] + bv, v[3] + bv) };
        *(uint2*)(C + (size_t)col * NSEQ + rowb) = p;
      } else {
#pragma unroll
        for (int r = 0; r < 4; ++r)
          C[(size_t)(rowb + r) * HID + col] = f2bf(v[r] + bv);
      }
    }
  }
}

// ---------------- out-proj GEMM: C = ctx(bf16) @ Wo(bf16)^T + bo, fp32 out ----------------
__global__ __launch_bounds__(256) void out_gemm(const uint16_t* __restrict__ Abf,
                                                const uint16_t* __restrict__ W,
                                                const float* __restrict__ bias,
                                                float* __restrict__ C) {
  __shared__ uint16_t a_s[2][64 * 40];
  __shared__ uint16_t b_s[2][64 * 40];
  int bidx = blockIdx.x;
  int i0 = (bidx >> 4) * 64, n0 = (bidx & 15) * 64;
  int t = threadIdx.x;
  int lane = t & 63, w = t >> 6;
  int fm = lane & 15, kq = lane >> 4;
  int wm = (w >> 1) * 32, wn = (w & 1) * 32;
  int ra = t >> 2, ca = (t & 3) * 8;
  const uint16_t* Ap = Abf + (size_t)(i0 + ra) * HID + ca;
  const uint16_t* Wp = W + (size_t)(n0 + ra) * HID + ca;
  floatx4 acc00 = {0,0,0,0}, acc01 = {0,0,0,0}, acc10 = {0,0,0,0}, acc11 = {0,0,0,0};
  uint4 ua = *(const uint4*)(Ap);
  uint4 ub = *(const uint4*)(Wp);
  *(uint4*)(&a_s[0][ra * 40 + ca]) = ua;
  *(uint4*)(&b_s[0][ra * 40 + ca]) = ub;
  for (int kt = 0; kt < 32; ++kt) {
    __syncthreads();
    int cur = kt & 1;
    if (kt < 31) {
      int ko = (kt + 1) * 32;
      ua = *(const uint4*)(Ap + ko);
      ub = *(const uint4*)(Wp + ko);
    }
    const uint16_t* as = &a_s[cur][0];
    const uint16_t* bs = &b_s[cur][0];
    bhalf8 a0 = *(bhalf8*)(as + (wm + fm) * 40 + kq * 8);
    bhalf8 a1 = *(bhalf8*)(as + (wm + 16 + fm) * 40 + kq * 8);
    bhalf8 b0 = *(bhalf8*)(bs + (wn + fm) * 40 + kq * 8);
    bhalf8 b1 = *(bhalf8*)(bs + (wn + 16 + fm) * 40 + kq * 8);
    acc00 = __builtin_amdgcn_mfma_f32_16x16x32_bf16(a0, b0, acc00, 0, 0, 0);
    acc01 = __builtin_amdgcn_mfma_f32_16x16x32_bf16(a0, b1, acc01, 0, 0, 0);
    acc10 = __builtin_amdgcn_mfma_f32_16x16x32_bf16(a1, b0, acc10, 0, 0, 0);
    acc11 = __builtin_amdgcn_mfma_f32_16x16x32_bf16(a1, b1, acc11, 0, 0, 0);
    if (kt < 31) {
      int nxt = cur ^ 1;
      *(uint4*)(&a_s[nxt][ra * 40 + ca]) = ua;
      *(uint4*)(&b_s[nxt][ra * 40 + ca]) = ub;
    }
  }
  int rb0 = kq * 4;
#define EPO(ACC, SM, SN)                                                   \
  {                                                                        \
    int rowb = i0 + wm + (SM)*16 + rb0;                                    \
    int col = n0 + wn + (SN)*16 + fm;                                      \
    float bv_ = bias[col];                                                 \
    _Pragma("unroll")                                                      \
    for (int rr = 0; rr < 4; ++rr)                                         \
      C[(size_t)(rowb + rr) * HID + col] = ACC[rr] + bv_;                  \
  }
  EPO(acc00, 0, 0) EPO(acc01, 0, 1) EPO(acc10, 1, 0) EPO(acc11, 1, 1)
#undef EPO
}

// ---------------- MFMA fused attention: R10 structure + Qs/C2P LDS union + Q-frags in regs ----------------
// Only change vs R10 (63.8 us): LDS 57.9 -> ~53.2 KB (3 blocks/CU) and 4 fewer
// ds_read_b128 per wave per tile. Per-tile barrier/softmax structure identical.
__global__ __launch_bounds__(256) void attn_kernel(const uint16_t* __restrict__ qg,
                                                   const uint16_t* __restrict__ kg,
                                                   const uint16_t* __restrict__ vtg,
                                                   const uint16_t* __restrict__ pkg,
                                                   const uint16_t* __restrict__ pqg,
                                                   uint16_t* __restrict__ ctx) {
  const float RSCALE = 0.07216878364870323f;  // 1/sqrt(192)
  __shared__ char QC2P[32 * 68 * 4];          // union: Qs[32][72] bf16 (pre-loop) / C2P[32][68] f32
  uint16_t (*Qs)[72] = (uint16_t(*)[72])QC2P;
  float (*C2P)[68] = (float(*)[68])QC2P;
  __shared__ uint16_t Ks[32][72];
  __shared__ uint16_t Vt[64][40];
  __shared__ uint16_t PKw[64][72];
  __shared__ uint16_t PQw[64][72];
  __shared__ float P2C[32][68];
  __shared__ float Sqk[32][36];
  __shared__ uint16_t Pbf[32][40];
  __shared__ float m_sm[32], l_sm[32], al_sm[32];

  int t = threadIdx.x;
  int lane = t & 63, w = t >> 6;
  int fm = lane & 15;
  int kq = lane >> 4;

  int b = blockIdx.x;
  int xcd = b & 7, slot = b >> 3;
  int h = xcd * 2 + (slot & 1);
  int i0 = (slot >> 1) * 32;
  int cb = h * DHEAD;

  // stage Q into union region, consume into registers, then region belongs to C2P
  {
    int r = t >> 3, chq = (t & 7) * 8;
    *(uint4*)(&Qs[r][chq]) = *(const uint4*)(qg + (size_t)(i0 + r) * HID + cb + chq);
  }
  if (t < 32) { m_sm[t] = -1e30f; l_sm[t] = 0.f; }
  __syncthreads();
  bhalf8 qf[2][2];
#pragma unroll
  for (int m2 = 0; m2 < 2; ++m2) {
    qf[m2][0] = *(bhalf8*)(&Qs[m2 * 16 + fm][kq * 8]);
    qf[m2][1] = *(bhalf8*)(&Qs[m2 * 16 + fm][kq * 8 + 32]);
  }

  floatx4 opv0 = {0,0,0,0}, opv1 = {0,0,0,0};
  int wn = w * 16;
  int smt = w >> 1, snt = w & 1;
  int i2 = t >> 3, jj = t & 7;

  int pr = t >> 3, pch = (t & 7) * 8;
  int rV = t >> 2, cV = (t & 3) * 8;
  const uint16_t* kb = kg + cb + pch;
  const uint16_t* vb = vtg + (size_t)(cb + rV) * HID + cV;
  const uint16_t* pkb = pkg + cb + pch;
  const uint16_t* pqb = pqg + cb + pch;

  uint4 rk, rv, rpk0, rpk1, rpq0, rpq1;
  {
    int j0 = 0;
    int rbase = KREL + i0 - j0 - 31;
    rk = *(const uint4*)(kb + (size_t)(j0 + pr) * HID);
    rv = *(const uint4*)(vb + j0);
    int rg0 = rbase + pr;
    int rg1 = rbase + pr + 32; if (rg1 > 2047) rg1 = 2047;
    rpk0 = *(const uint4*)(pkb + (size_t)rg0 * HID);
    rpk1 = *(const uint4*)(pkb + (size_t)rg1 * HID);
    rpq0 = *(const uint4*)(pqb + (size_t)rg0 * HID);
    rpq1 = *(const uint4*)(pqb + (size_t)rg1 * HID);
  }

  for (int jt = 0; jt < NSEQ / 32; ++jt) {
    __syncthreads();  // barrier A: prior tile consumed (also drains qf reads on jt==0)
    *(uint4*)(&Ks[pr][pch]) = rk;
    *(uint4*)(&Vt[rV][cV]) = rv;
    *(uint4*)(&PKw[pr][pch]) = rpk0;
    *(uint4*)(&PKw[pr + 32][pch]) = rpk1;
    *(uint4*)(&PQw[pr][pch]) = rpq0;
    *(uint4*)(&PQw[pr + 32][pch]) = rpq1;
    __syncthreads();  // barrier B: staging visible

    if (jt + 1 < NSEQ / 32) {
      int j0 = (jt + 1) * 32;
      int rbase = KREL + i0 - j0 - 31;
      rk = *(const uint4*)(kb + (size_t)(j0 + pr) * HID);
      rv = *(const uint4*)(vb + j0);
      int rg0 = rbase + pr; if (rg0 < 0) rg0 = 0;
      int rg1 = rbase + pr + 32; if (rg1 > 2047) rg1 = 2047;
      rpk0 = *(const uint4*)(pkb + (size_t)rg0 * HID);
      rpk1 = *(const uint4*)(pkb + (size_t)rg1 * HID);
      rpq0 = *(const uint4*)(pqb + (size_t)rg0 * HID);
      rpq1 = *(const uint4*)(pqb + (size_t)rg1 * HID);
    }

    // ---- stage 1: window GEMMs + Sqk (wave-uniform branch; A-frags from regs where possible) ----
    if (w < 2) {
      // waves 0,1: C2P = Q @ PKwin^T, A-frags = qf (regs)
      int ntb = w * 2;
#pragma unroll
      for (int nt = ntb; nt < ntb + 2; ++nt) {
        bhalf8 b0 = *(bhalf8*)(&PKw[nt * 16 + fm][kq * 8]);
        bhalf8 b1 = *(bhalf8*)(&PKw[nt * 16 + fm][kq * 8 + 32]);
#pragma unroll
        for (int mt = 0; mt < 2; ++mt) {
          floatx4 acc = {0,0,0,0};
          acc = __builtin_amdgcn_mfma_f32_16x16x32_bf16(qf[mt][0], b0, acc, 0, 0, 0);
          acc = __builtin_amdgcn_mfma_f32_16x16x32_bf16(qf[mt][1], b1, acc, 0, 0, 0);
#pragma unroll
          for (int r = 0; r < 4; ++r)
            C2P[mt * 16 + kq * 4 + r][nt * 16 + fm] = acc[r];
        }
      }
      // Sqk subtile (smt=0, snt=w)
      bhalf8 kb0 = *(bhalf8*)(&Ks[snt * 16 + fm][kq * 8]);
      bhalf8 kb1 = *(bhalf8*)(&Ks[snt * 16 + fm][kq * 8 + 32]);
      floatx4 sacc = {0,0,0,0};
      sacc = __builtin_amdgcn_mfma_f32_16x16x32_bf16(qf[0][0], kb0, sacc, 0, 0, 0);
      sacc = __builtin_amdgcn_mfma_f32_16x16x32_bf16(qf[0][1], kb1, sacc, 0, 0, 0);
#pragma unroll
      for (int r = 0; r < 4; ++r)
        Sqk[kq * 4 + r][snt * 16 + fm] = sacc[r];
    } else {
      // waves 2,3: P2C = K @ PQwin^T, A-frags = ka (4 LDS reads)
      int ntb = (w & 1) * 2;
      bhalf8 ka[2][2];
#pragma unroll
      for (int mt = 0; mt < 2; ++mt) {
        ka[mt][0] = *(bhalf8*)(&Ks[mt * 16 + fm][kq * 8]);
        ka[mt][1] = *(bhalf8*)(&Ks[mt * 16 + fm][kq * 8 + 32]);
      }
#pragma unroll
      for (int nt = ntb; nt < ntb + 2; ++nt) {
        bhalf8 b0 = *(bhalf8*)(&PQw[nt * 16 + fm][kq * 8]);
        bhalf8 b1 = *(bhalf8*)(&PQw[nt * 16 + fm][kq * 8 + 32]);
#pragma unroll
        for (int mt = 0; mt < 2; ++mt) {
          floatx4 acc = {0,0,0,0};
          acc = __builtin_amdgcn_mfma_f32_16x16x32_bf16(ka[mt][0], b0, acc, 0, 0, 0);
          acc = __builtin_amdgcn_mfma_f32_16x16x32_bf16(ka[mt][1], b1, acc, 0, 0, 0);
#pragma unroll
          for (int r = 0; r < 4; ++r)
            P2C[mt * 16 + kq * 4 + r][nt * 16 + fm] = acc[r];
        }
      }
      // Sqk subtile (smt=1, snt=w&1)
      floatx4 sacc = {0,0,0,0};
      sacc = __builtin_amdgcn_mfma_f32_16x16x32_bf16(qf[1][0], ka[snt][0], sacc, 0, 0, 0);
      sacc = __builtin_amdgcn_mfma_f32_16x16x32_bf16(qf[1][1], ka[snt][1], sacc, 0, 0, 0);
#pragma unroll
      for (int r = 0; r < 4; ++r)
        Sqk[16 + kq * 4 + r][snt * 16 + fm] = sacc[r];
    }
    __syncthreads();  // barrier C

    // ---- stage 2: gather + combine + online softmax ----
    {
      float sv[4];
#pragma unroll
      for (int q = 0; q < 4; ++q) {
        int j = jj + 8 * q;
        int rr = i2 - j + 31;  // in [0,62]
        sv[q] = (Sqk[i2][j] + C2P[i2][rr] + P2C[j][rr]) * RSCALE;
      }
      float mx = fmaxf(fmaxf(sv[0], sv[1]), fmaxf(sv[2], sv[3]));
      mx = fmaxf(mx, __shfl_xor(mx, 1));
      mx = fmaxf(mx, __shfl_xor(mx, 2));
      mx = fmaxf(mx, __shfl_xor(mx, 4));
      float m_old = m_sm[i2];
      float m_new = fmaxf(m_old, mx);
      float al = __expf(m_old - m_new);
      float ts = 0.f;
#pragma unroll
      for (int q = 0; q < 4; ++q) {
        float e = __expf(sv[q] - m_new);
        Pbf[i2][jj + 8 * q] = f2bf(e);
        ts += e;
      }
      ts += __shfl_xor(ts, 1);
      ts += __shfl_xor(ts, 2);
      ts += __shfl_xor(ts, 4);
      if (jj == 0) { m_sm[i2] = m_new; l_sm[i2] = l_sm[i2] * al + ts; al_sm[i2] = al; }
    }
    __syncthreads();  // barrier D

    // ---- stage 3: PV via MFMA ----
    {
#pragma unroll
      for (int r = 0; r < 4; ++r) {
        opv0[r] *= al_sm[kq * 4 + r];
        opv1[r] *= al_sm[16 + kq * 4 + r];
      }
      bhalf8 vbf = *(bhalf8*)(&Vt[wn + fm][kq * 8]);
      bhalf8 pa0 = *(bhalf8*)(&Pbf[fm][kq * 8]);
      bhalf8 pa1 = *(bhalf8*)(&Pbf[16 + fm][kq * 8]);
      opv0 = __builtin_amdgcn_mfma_f32_16x16x32_bf16(pa0, vbf, opv0, 0, 0, 0);
      opv1 = __builtin_amdgcn_mfma_f32_16x16x32_bf16(pa1, vbf, opv1, 0, 0, 0);
    }
  }

#pragma unroll
  for (int r = 0; r < 4; ++r) {
    int ia = kq * 4 + r, ib = 16 + kq * 4 + r;
    float la = 1.0f / l_sm[ia], lb = 1.0f / l_sm[ib];
    ctx[(size_t)(i0 + ia) * HID + cb + wn + fm] = f2bf(opv0[r] * la);
    ctx[(size_t)(i0 + ib) * HID + cb + wn + fm] = f2bf(opv1[r] * lb);
  }
}

// ---------------- residual + LayerNorm ----------------
__global__ __launch_bounds__(256) void ln_kernel(const float* __restrict__ xin,
                                                 const float* __restrict__ hs,
                                                 const float* __restrict__ g,
                                                 const float* __restrict__ b,
                                                 float* __restrict__ y) {
  int row = blockIdx.x, t = threadIdx.x;
  int c = t * 4;
  float4 a = *(const float4*)(xin + (size_t)row * HID + c);
  float4 hv = *(const float4*)(hs + (size_t)row * HID + c);
  float x0 = a.x + hv.x, x1 = a.y + hv.y, x2 = a.z + hv.z, x3 = a.w + hv.w;
  float s = x0 + x1 + x2 + x3;
  float sq = x0 * x0 + x1 * x1 + x2 * x2 + x3 * x3;
  for (int off = 32; off; off >>= 1) {
    s += __shfl_xor(s, off);
    sq += __shfl_xor(sq, off);
  }
  __shared__ float rs[4], rq[4];
  int w = t >> 6, lane = t & 63;
  if (lane == 0) { rs[w] = s; rq[w] = sq; }
  __syncthreads();
  s = rs[0] + rs[1] + rs[2] + rs[3];
  sq = rq[0] + rq[1] + rq[2] + rq[3];
  float mu = s * (1.0f / HID);
  float var = sq * (1.0f / HID) - mu * mu;
  float rstd = rsqrtf(var + 1e-7f);
  float4 gg = *(const float4*)(g + c);
  float4 bb = *(const float4*)(b + c);
  float4 out;
  out.x = (x0 - mu) * rstd * gg.x + bb.x;
  out.y = (x1 - mu) * rstd * gg.y + bb.y;
  out.z = (x2 - mu) * rstd * gg.z + bb.z;
  out.w = (x3 - mu) * rstd * gg.w + bb.w;
  *(float4*)(y + (size_t)row * HID + c) = out;
}

extern "C" void kernel_launch(void* const* d_in, const int* in_sizes, int n_in,
                              void* d_out, int out_size, void* d_ws, size_t ws_size,
                              hipStream_t stream) {
  const float* hs  = (const float*)d_in[0];
  const float* rel = (const float*)d_in[1];
  const float* Wq  = (const float*)d_in[2];  const float* bq  = (const float*)d_in[3];
  const float* Wk  = (const float*)d_in[4];  const float* bk  = (const float*)d_in[5];
  const float* Wv  = (const float*)d_in[6];  const float* bv  = (const float*)d_in[7];
  const float* Wpk = (const float*)d_in[8];  const float* bpk = (const float*)d_in[9];
  const float* Wpq = (const float*)d_in[10]; const float* bpq = (const float*)d_in[11];
  const float* Wo  = (const float*)d_in[12]; const float* bo  = (const float*)d_in[13];
  const float* lng = (const float*)d_in[14]; const float* lnb = (const float*)d_in[15];

  char* ws = (char*)d_ws;
  const size_t MB = 1024 * 1024;
  uint16_t* q_bf   = (uint16_t*)(ws + 0 * MB);
  uint16_t* k_bf   = (uint16_t*)(ws + 2 * MB);
  uint16_t* vt_bf  = (uint16_t*)(ws + 4 * MB);   // transposed [d][i]
  uint16_t* pk_bf  = (uint16_t*)(ws + 6 * MB);
  uint16_t* pq_bf  = (uint16_t*)(ws + 10 * MB);
  uint16_t* ctx_bf = (uint16_t*)(ws + 14 * MB);
  float*    out_f  = (float*)   (ws + 16 * MB);
  uint16_t* hs_bf  = (uint16_t*)(ws + 20 * MB);
  uint16_t* rel_bf = (uint16_t*)(ws + 22 * MB);
  uint16_t* Wq_bf  = (uint16_t*)(ws + 26 * MB);
  uint16_t* Wk_bf  = (uint16_t*)(ws + 28 * MB);
  uint16_t* Wv_bf  = (uint16_t*)(ws + 30 * MB);
  uint16_t* Wpk_bf = (uint16_t*)(ws + 32 * MB);
  uint16_t* Wpq_bf = (uint16_t*)(ws + 34 * MB);
  uint16_t* Wo_bf  = (uint16_t*)(ws + 36 * MB);  // total 38 MB

  dim3 blk(256);

  Cast8 c8;
  c8.src[0] = hs;  c8.dst[0] = hs_bf;  c8.n[0] = 1024 * 1024;
  c8.src[1] = rel; c8.dst[1] = rel_bf; c8.n[1] = 2048 * 1024;
  c8.src[2] = Wq;  c8.dst[2] = Wq_bf;  c8.n[2] = 1024 * 1024;
  c8.src[3] = Wk;  c8.dst[3] = Wk_bf;  c8.n[3] = 1024 * 1024;
  c8.src[4] = Wv;  c8.dst[4] = Wv_bf;  c8.n[4] = 1024 * 1024;
  c8.src[5] = Wpk; c8.dst[5] = Wpk_bf; c8.n[5] = 1024 * 1024;
  c8.src[6] = Wpq; c8.dst[6] = Wpq_bf; c8.n[6] = 1024 * 1024;
  c8.src[7] = Wo;  c8.dst[7] = Wo_bf;  c8.n[7] = 1024 * 1024;
  cast8_kernel<<<dim3(1024, 8), blk, 0, stream>>>(c8);

  ProjArgs pa;
  pa.A[0] = hs_bf;  pa.A[1] = hs_bf;  pa.A[2] = hs_bf;  pa.A[3] = rel_bf; pa.A[4] = rel_bf;
  pa.W[0] = Wq_bf;  pa.W[1] = Wk_bf;  pa.W[2] = Wv_bf;  pa.W[3] = Wpk_bf; pa.W[4] = Wpq_bf;
  pa.bias[0] = bq;  pa.bias[1] = bk;  pa.bias[2] = bv;  pa.bias[3] = bpk; pa.bias[4] = bpq;
  pa.C[0] = q_bf; pa.C[1] = k_bf; pa.C[2] = vt_bf; pa.C[3] = pk_bf; pa.C[4] = pq_bf;
  pa.trans[0] = 0; pa.trans[1] = 0; pa.trans[2] = 1; pa.trans[3] = 0; pa.trans[4] = 0;
  proj_gemm<<<dim3(448), blk, 0, stream>>>(pa);

  attn_kernel<<<dim3(512), blk, 0, stream>>>(q_bf, k_bf, vt_bf, pk_bf, pq_bf, ctx_bf);

  out_gemm<<<dim3(256), blk, 0, stream>>>(ctx_bf, Wo_bf, bo, out_f);

  ln_kernel<<<dim3(1024), blk, 0, stream>>>(out_f, hs, lng, lnb, (float*)d_out);
}

// Round 12
// 208.224 us; speedup vs baseline: 1.4432x; 1.4432x over previous
//
#include <hip/hip_runtime.h>
#include <stdint.h>

#define HID 1024
#define NSEQ 1024
#define KREL 1024
#define NHEAD 16
#define DHEAD 64

typedef __attribute__((ext_vector_type(8))) short bhalf8;
typedef __attribute__((ext_vector_type(4))) float floatx4;

__device__ inline uint16_t f2bf(float f) {
  union { float f; uint32_t u; } c; c.f = f;
  uint32_t u = c.u;
  return (uint16_t)((u + 0x7fffu + ((u >> 16) & 1u)) >> 16);
}
__device__ inline uint32_t pkbf(float a, float b) {
  union { float f; uint32_t u; } x, y; x.f = a; y.f = b;
#if __has_builtin(__builtin_amdgcn_perm)
  return __builtin_amdgcn_perm(x.u + 0x8000u, y.u + 0x8000u, 0x03020706u);
#else
  return ((x.u + 0x8000u) >> 16) | ((y.u + 0x8000u) & 0xffff0000u);
#endif
}

// ---------------- fused fp32 -> bf16 casts (8 segments) ----------------
struct Cast8 {
  const float* src[8];
  uint16_t* dst[8];
  int n[8];
};
__global__ __launch_bounds__(256) void cast8_kernel(Cast8 c) {
  int seg = blockIdx.y;
  int n = c.n[seg];
  const float* s = c.src[seg];
  uint16_t* d = c.dst[seg];
  for (int idx = (blockIdx.x * 256 + threadIdx.x) * 4; idx < n; idx += 1024 * 256 * 4) {
    float4 v = *(const float4*)(s + idx);
    ushort4 o;
    o.x = f2bf(v.x); o.y = f2bf(v.y); o.z = f2bf(v.z); o.w = f2bf(v.w);
    *(ushort4*)(d + idx) = o;
  }
}

// ---------------- unified projection GEMM (bf16 in): 128x128 tile, BK=32, sync dbuf ----------------
// (R7/R9/R10-measured best.) z==2 (V) writes transposed Vt[d][i].
struct ProjArgs {
  const uint16_t* A[5];
  const uint16_t* W[5];
  const float* bias[5];
  uint16_t* C[5];
  int trans[5];
};
__global__ __launch_bounds__(256) void proj_gemm(ProjArgs pa) {
  __shared__ uint16_t a_s[2][128 * 40];
  __shared__ uint16_t b_s[2][128 * 40];
  int bidx = blockIdx.x;
  int xcd = bidx & 7, idx = bidx >> 3;
  int g = xcd * 7 + (idx >> 3);
  int nt = idx & 7;
  int z, mt;
  if (g < 24) { z = g >> 3; mt = g & 7; }
  else { int g2 = g - 24; z = 3 + (g2 >> 4); mt = g2 & 15; }
  const uint16_t* A = pa.A[z];
  const uint16_t* W = pa.W[z];
  int i0 = mt * 128, n0 = nt * 128;

  int t = threadIdx.x;
  int lane = t & 63, w = t >> 6;
  int fm = lane & 15, kq = lane >> 4;
  int wm = (w >> 1) * 64, wn = (w & 1) * 64;

  int ra = t >> 1, ca = (t & 1) * 16;
  const uint16_t* Ap = A + (size_t)(i0 + ra) * HID + ca;
  const uint16_t* Wp = W + (size_t)(n0 + ra) * HID + ca;

  floatx4 acc[4][4] = {};

  uint4 ua0 = *(const uint4*)(Ap);
  uint4 ua1 = *(const uint4*)(Ap + 8);
  uint4 ub0 = *(const uint4*)(Wp);
  uint4 ub1 = *(const uint4*)(Wp + 8);
  *(uint4*)(&a_s[0][ra * 40 + ca]) = ua0;
  *(uint4*)(&a_s[0][ra * 40 + ca + 8]) = ua1;
  *(uint4*)(&b_s[0][ra * 40 + ca]) = ub0;
  *(uint4*)(&b_s[0][ra * 40 + ca + 8]) = ub1;

  for (int kt = 0; kt < 32; ++kt) {
    __syncthreads();
    int cur = kt & 1;
    if (kt < 31) {
      int ko = (kt + 1) * 32;
      ua0 = *(const uint4*)(Ap + ko);
      ua1 = *(const uint4*)(Ap + ko + 8);
      ub0 = *(const uint4*)(Wp + ko);
      ub1 = *(const uint4*)(Wp + ko + 8);
    }
    const uint16_t* as = &a_s[cur][0];
    const uint16_t* bs = &b_s[cur][0];
    bhalf8 af[4], bf[4];
#pragma unroll
    for (int m2 = 0; m2 < 4; ++m2)
      af[m2] = *(bhalf8*)(as + (wm + m2 * 16 + fm) * 40 + kq * 8);
#pragma unroll
    for (int n2 = 0; n2 < 4; ++n2)
      bf[n2] = *(bhalf8*)(bs + (wn + n2 * 16 + fm) * 40 + kq * 8);
#pragma unroll
    for (int m2 = 0; m2 < 4; ++m2)
#pragma unroll
      for (int n2 = 0; n2 < 4; ++n2)
        acc[m2][n2] = __builtin_amdgcn_mfma_f32_16x16x32_bf16(af[m2], bf[n2], acc[m2][n2], 0, 0, 0);
    if (kt < 31) {
      int nxt = cur ^ 1;
      *(uint4*)(&a_s[nxt][ra * 40 + ca]) = ua0;
      *(uint4*)(&a_s[nxt][ra * 40 + ca + 8]) = ua1;
      *(uint4*)(&b_s[nxt][ra * 40 + ca]) = ub0;
      *(uint4*)(&b_s[nxt][ra * 40 + ca + 8]) = ub1;
    }
  }

  const float* bias = pa.bias[z];
  uint16_t* C = pa.C[z];
  int tr = pa.trans[z];
#pragma unroll
  for (int m2 = 0; m2 < 4; ++m2) {
    int rowb = i0 + wm + m2 * 16 + kq * 4;
#pragma unroll
    for (int n2 = 0; n2 < 4; ++n2) {
      int col = n0 + wn + n2 * 16 + fm;
      float bv = bias[col];
      floatx4 v = acc[m2][n2];
      if (tr) {
        uint2 p = { pkbf(v[0] + bv, v[1] + bv), pkbf(v[2] + bv, v[3] + bv) };
        *(uint2*)(C + (size_t)col * NSEQ + rowb) = p;
      } else {
#pragma unroll
        for (int r = 0; r < 4; ++r)
          C[(size_t)(rowb + r) * HID + col] = f2bf(v[r] + bv);
      }
    }
  }
}

// ---------------- out-proj GEMM: C = ctx(bf16) @ Wo(bf16)^T + bo, fp32 out ----------------
__global__ __launch_bounds__(256) void out_gemm(const uint16_t* __restrict__ Abf,
                                                const uint16_t* __restrict__ W,
                                                const float* __restrict__ bias,
                                                float* __restrict__ C) {
  __shared__ uint16_t a_s[2][64 * 40];
  __shared__ uint16_t b_s[2][64 * 40];
  int bidx = blockIdx.x;
  int i0 = (bidx >> 4) * 64, n0 = (bidx & 15) * 64;
  int t = threadIdx.x;
  int lane = t & 63, w = t >> 6;
  int fm = lane & 15, kq = lane >> 4;
  int wm = (w >> 1) * 32, wn = (w & 1) * 32;
  int ra = t >> 2, ca = (t & 3) * 8;
  const uint16_t* Ap = Abf + (size_t)(i0 + ra) * HID + ca;
  const uint16_t* Wp = W + (size_t)(n0 + ra) * HID + ca;
  floatx4 acc00 = {0,0,0,0}, acc01 = {0,0,0,0}, acc10 = {0,0,0,0}, acc11 = {0,0,0,0};
  uint4 ua = *(const uint4*)(Ap);
  uint4 ub = *(const uint4*)(Wp);
  *(uint4*)(&a_s[0][ra * 40 + ca]) = ua;
  *(uint4*)(&b_s[0][ra * 40 + ca]) = ub;
  for (int kt = 0; kt < 32; ++kt) {
    __syncthreads();
    int cur = kt & 1;
    if (kt < 31) {
      int ko = (kt + 1) * 32;
      ua = *(const uint4*)(Ap + ko);
      ub = *(const uint4*)(Wp + ko);
    }
    const uint16_t* as = &a_s[cur][0];
    const uint16_t* bs = &b_s[cur][0];
    bhalf8 a0 = *(bhalf8*)(as + (wm + fm) * 40 + kq * 8);
    bhalf8 a1 = *(bhalf8*)(as + (wm + 16 + fm) * 40 + kq * 8);
    bhalf8 b0 = *(bhalf8*)(bs + (wn + fm) * 40 + kq * 8);
    bhalf8 b1 = *(bhalf8*)(bs + (wn + 16 + fm) * 40 + kq * 8);
    acc00 = __builtin_amdgcn_mfma_f32_16x16x32_bf16(a0, b0, acc00, 0, 0, 0);
    acc01 = __builtin_amdgcn_mfma_f32_16x16x32_bf16(a0, b1, acc01, 0, 0, 0);
    acc10 = __builtin_amdgcn_mfma_f32_16x16x32_bf16(a1, b0, acc10, 0, 0, 0);
    acc11 = __builtin_amdgcn_mfma_f32_16x16x32_bf16(a1, b1, acc11, 0, 0, 0);
    if (kt < 31) {
      int nxt = cur ^ 1;
      *(uint4*)(&a_s[nxt][ra * 40 + ca]) = ua;
      *(uint4*)(&b_s[nxt][ra * 40 + ca]) = ub;
    }
  }
  int rb0 = kq * 4;
#define EPO(ACC, SM, SN)                                                   \
  {                                                                        \
    int rowb = i0 + wm + (SM)*16 + rb0;                                    \
    int col = n0 + wn + (SN)*16 + fm;                                      \
    float bv_ = bias[col];                                                 \
    _Pragma("unroll")                                                      \
    for (int rr = 0; rr < 4; ++rr)                                         \
      C[(size_t)(rowb + rr) * HID + col] = ACC[rr] + bv_;                  \
  }
  EPO(acc00, 0, 0) EPO(acc01, 0, 1) EPO(acc10, 1, 0) EPO(acc11, 1, 1)
#undef EPO
}

// ---------------- MFMA fused attention (R5/R8/R10-verified structure — do not restructure) ----------------
// Measured 63.8 us x3. Known-bad variants: register-held A-frags across the tile loop,
// per-wave divergent stage-1 bodies, split-j partials, fixed-max+bf16 intermediates.
__global__ __launch_bounds__(256) void attn_kernel(const uint16_t* __restrict__ qg,
                                                   const uint16_t* __restrict__ kg,
                                                   const uint16_t* __restrict__ vtg,
                                                   const uint16_t* __restrict__ pkg,
                                                   const uint16_t* __restrict__ pqg,
                                                   uint16_t* __restrict__ ctx) {
  const float RSCALE = 0.07216878364870323f;  // 1/sqrt(192)
  __shared__ uint16_t Qs[32][72];
  __shared__ uint16_t Ks[32][72];
  __shared__ uint16_t Vt[64][40];
  __shared__ uint16_t PKw[64][72];
  __shared__ uint16_t PQw[64][72];
  __shared__ float C2P[32][68];
  __shared__ float P2C[32][68];
  __shared__ float Sqk[32][36];
  __shared__ uint16_t Pbf[32][40];
  __shared__ float m_sm[32], l_sm[32], al_sm[32];

  int t = threadIdx.x;
  int lane = t & 63, w = t >> 6;
  int fm = lane & 15;
  int kq = lane >> 4;

  int b = blockIdx.x;
  int xcd = b & 7, slot = b >> 3;
  int h = xcd * 2 + (slot & 1);
  int i0 = (slot >> 1) * 32;
  int cb = h * DHEAD;

  {
    int r = t >> 3, chq = (t & 7) * 8;
    *(uint4*)(&Qs[r][chq]) = *(const uint4*)(qg + (size_t)(i0 + r) * HID + cb + chq);
  }
  if (t < 32) { m_sm[t] = -1e30f; l_sm[t] = 0.f; }

  floatx4 opv0 = {0,0,0,0}, opv1 = {0,0,0,0};
  int wn = w * 16;
  int smt = w >> 1, snt = w & 1;
  int i2 = t >> 3, jj = t & 7;

  int pr = t >> 3, pch = (t & 7) * 8;
  int rV = t >> 2, cV = (t & 3) * 8;
  const uint16_t* kb = kg + cb + pch;
  const uint16_t* vb = vtg + (size_t)(cb + rV) * HID + cV;
  const uint16_t* pkb = pkg + cb + pch;
  const uint16_t* pqb = pqg + cb + pch;

  uint4 rk, rv, rpk0, rpk1, rpq0, rpq1;
  {
    int j0 = 0;
    int rbase = KREL + i0 - j0 - 31;
    rk = *(const uint4*)(kb + (size_t)(j0 + pr) * HID);
    rv = *(const uint4*)(vb + j0);
    int rg0 = rbase + pr;
    int rg1 = rbase + pr + 32; if (rg1 > 2047) rg1 = 2047;
    rpk0 = *(const uint4*)(pkb + (size_t)rg0 * HID);
    rpk1 = *(const uint4*)(pkb + (size_t)rg1 * HID);
    rpq0 = *(const uint4*)(pqb + (size_t)rg0 * HID);
    rpq1 = *(const uint4*)(pqb + (size_t)rg1 * HID);
  }

  for (int jt = 0; jt < NSEQ / 32; ++jt) {
    __syncthreads();
    *(uint4*)(&Ks[pr][pch]) = rk;
    *(uint4*)(&Vt[rV][cV]) = rv;
    *(uint4*)(&PKw[pr][pch]) = rpk0;
    *(uint4*)(&PKw[pr + 32][pch]) = rpk1;
    *(uint4*)(&PQw[pr][pch]) = rpq0;
    *(uint4*)(&PQw[pr + 32][pch]) = rpq1;
    __syncthreads();

    if (jt + 1 < NSEQ / 32) {
      int j0 = (jt + 1) * 32;
      int rbase = KREL + i0 - j0 - 31;
      rk = *(const uint4*)(kb + (size_t)(j0 + pr) * HID);
      rv = *(const uint4*)(vb + j0);
      int rg0 = rbase + pr; if (rg0 < 0) rg0 = 0;
      int rg1 = rbase + pr + 32; if (rg1 > 2047) rg1 = 2047;
      rpk0 = *(const uint4*)(pkb + (size_t)rg0 * HID);
      rpk1 = *(const uint4*)(pkb + (size_t)rg1 * HID);
      rpq0 = *(const uint4*)(pqb + (size_t)rg0 * HID);
      rpq1 = *(const uint4*)(pqb + (size_t)rg1 * HID);
    }

    // ---- stage 1: window GEMMs + Sqk (wave-uniform pointer select; A-frags from LDS) ----
    {
      const uint16_t* Asrc = (w < 2) ? &Qs[0][0] : &Ks[0][0];
      const uint16_t* Bsrc = (w < 2) ? &PKw[0][0] : &PQw[0][0];
      float* Cdst = (w < 2) ? &C2P[0][0] : &P2C[0][0];
      int ntb = (w & 1) * 2;
#pragma unroll
      for (int mt = 0; mt < 2; ++mt) {
        bhalf8 a0 = *(bhalf8*)(Asrc + (mt * 16 + fm) * 72 + kq * 8);
        bhalf8 a1 = *(bhalf8*)(Asrc + (mt * 16 + fm) * 72 + kq * 8 + 32);
#pragma unroll
        for (int nt = ntb; nt < ntb + 2; ++nt) {
          bhalf8 b0 = *(bhalf8*)(Bsrc + (nt * 16 + fm) * 72 + kq * 8);
          bhalf8 b1 = *(bhalf8*)(Bsrc + (nt * 16 + fm) * 72 + kq * 8 + 32);
          floatx4 acc = {0,0,0,0};
          acc = __builtin_amdgcn_mfma_f32_16x16x32_bf16(a0, b0, acc, 0, 0, 0);
          acc = __builtin_amdgcn_mfma_f32_16x16x32_bf16(a1, b1, acc, 0, 0, 0);
#pragma unroll
          for (int r = 0; r < 4; ++r)
            Cdst[(mt * 16 + kq * 4 + r) * 68 + nt * 16 + fm] = acc[r];
        }
      }
      bhalf8 qa0 = *(bhalf8*)(&Qs[smt * 16 + fm][kq * 8]);
      bhalf8 qa1 = *(bhalf8*)(&Qs[smt * 16 + fm][kq * 8 + 32]);
      bhalf8 kb0 = *(bhalf8*)(&Ks[snt * 16 + fm][kq * 8]);
      bhalf8 kb1 = *(bhalf8*)(&Ks[snt * 16 + fm][kq * 8 + 32]);
      floatx4 sacc = {0,0,0,0};
      sacc = __builtin_amdgcn_mfma_f32_16x16x32_bf16(qa0, kb0, sacc, 0, 0, 0);
      sacc = __builtin_amdgcn_mfma_f32_16x16x32_bf16(qa1, kb1, sacc, 0, 0, 0);
#pragma unroll
      for (int r = 0; r < 4; ++r)
        Sqk[smt * 16 + kq * 4 + r][snt * 16 + fm] = sacc[r];
    }
    __syncthreads();

    // ---- stage 2: gather + combine + online softmax ----
    {
      float sv[4];
#pragma unroll
      for (int q = 0; q < 4; ++q) {
        int j = jj + 8 * q;
        int rr = i2 - j + 31;  // in [0,62]
        sv[q] = (Sqk[i2][j] + C2P[i2][rr] + P2C[j][rr]) * RSCALE;
      }
      float mx = fmaxf(fmaxf(sv[0], sv[1]), fmaxf(sv[2], sv[3]));
      mx = fmaxf(mx, __shfl_xor(mx, 1));
      mx = fmaxf(mx, __shfl_xor(mx, 2));
      mx = fmaxf(mx, __shfl_xor(mx, 4));
      float m_old = m_sm[i2];
      float m_new = fmaxf(m_old, mx);
      float al = __expf(m_old - m_new);
      float ts = 0.f;
#pragma unroll
      for (int q = 0; q < 4; ++q) {
        float e = __expf(sv[q] - m_new);
        Pbf[i2][jj + 8 * q] = f2bf(e);
        ts += e;
      }
      ts += __shfl_xor(ts, 1);
      ts += __shfl_xor(ts, 2);
      ts += __shfl_xor(ts, 4);
      if (jj == 0) { m_sm[i2] = m_new; l_sm[i2] = l_sm[i2] * al + ts; al_sm[i2] = al; }
    }
    __syncthreads();

    // ---- stage 3: PV via MFMA ----
    {
#pragma unroll
      for (int r = 0; r < 4; ++r) {
        opv0[r] *= al_sm[kq * 4 + r];
        opv1[r] *= al_sm[16 + kq * 4 + r];
      }
      bhalf8 vbf = *(bhalf8*)(&Vt[wn + fm][kq * 8]);
      bhalf8 pa0 = *(bhalf8*)(&Pbf[fm][kq * 8]);
      bhalf8 pa1 = *(bhalf8*)(&Pbf[16 + fm][kq * 8]);
      opv0 = __builtin_amdgcn_mfma_f32_16x16x32_bf16(pa0, vbf, opv0, 0, 0, 0);
      opv1 = __builtin_amdgcn_mfma_f32_16x16x32_bf16(pa1, vbf, opv1, 0, 0, 0);
    }
  }

#pragma unroll
  for (int r = 0; r < 4; ++r) {
    int ia = kq * 4 + r, ib = 16 + kq * 4 + r;
    float la = 1.0f / l_sm[ia], lb = 1.0f / l_sm[ib];
    ctx[(size_t)(i0 + ia) * HID + cb + wn + fm] = f2bf(opv0[r] * la);
    ctx[(size_t)(i0 + ib) * HID + cb + wn + fm] = f2bf(opv1[r] * lb);
  }
}

// ---------------- residual + LayerNorm ----------------
__global__ __launch_bounds__(256) void ln_kernel(const float* __restrict__ xin,
                                                 const float* __restrict__ hs,
                                                 const float* __restrict__ g,
                                                 const float* __restrict__ b,
                                                 float* __restrict__ y) {
  int row = blockIdx.x, t = threadIdx.x;
  int c = t * 4;
  float4 a = *(const float4*)(xin + (size_t)row * HID + c);
  float4 hv = *(const float4*)(hs + (size_t)row * HID + c);
  float x0 = a.x + hv.x, x1 = a.y + hv.y, x2 = a.z + hv.z, x3 = a.w + hv.w;
  float s = x0 + x1 + x2 + x3;
  float sq = x0 * x0 + x1 * x1 + x2 * x2 + x3 * x3;
  for (int off = 32; off; off >>= 1) {
    s += __shfl_xor(s, off);
    sq += __shfl_xor(sq, off);
  }
  __shared__ float rs[4], rq[4];
  int w = t >> 6, lane = t & 63;
  if (lane == 0) { rs[w] = s; rq[w] = sq; }
  __syncthreads();
  s = rs[0] + rs[1] + rs[2] + rs[3];
  sq = rq[0] + rq[1] + rq[2] + rq[3];
  float mu = s * (1.0f / HID);
  float var = sq * (1.0f / HID) - mu * mu;
  float rstd = rsqrtf(var + 1e-7f);
  float4 gg = *(const float4*)(g + c);
  float4 bb = *(const float4*)(b + c);
  float4 out;
  out.x = (x0 - mu) * rstd * gg.x + bb.x;
  out.y = (x1 - mu) * rstd * gg.y + bb.y;
  out.z = (x2 - mu) * rstd * gg.z + bb.z;
  out.w = (x3 - mu) * rstd * gg.w + bb.w;
  *(float4*)(y + (size_t)row * HID + c) = out;
}

extern "C" void kernel_launch(void* const* d_in, const int* in_sizes, int n_in,
                              void* d_out, int out_size, void* d_ws, size_t ws_size,
                              hipStream_t stream) {
  const float* hs  = (const float*)d_in[0];
  const float* rel = (const float*)d_in[1];
  const float* Wq  = (const float*)d_in[2];  const float* bq  = (const float*)d_in[3];
  const float* Wk  = (const float*)d_in[4];  const float* bk  = (const float*)d_in[5];
  const float* Wv  = (const float*)d_in[6];  const float* bv  = (const float*)d_in[7];
  const float* Wpk = (const float*)d_in[8];  const float* bpk = (const float*)d_in[9];
  const float* Wpq = (const float*)d_in[10]; const float* bpq = (const float*)d_in[11];
  const float* Wo  = (const float*)d_in[12]; const float* bo  = (const float*)d_in[13];
  const float* lng = (const float*)d_in[14]; const float* lnb = (const float*)d_in[15];

  char* ws = (char*)d_ws;
  const size_t MB = 1024 * 1024;
  uint16_t* q_bf   = (uint16_t*)(ws + 0 * MB);
  uint16_t* k_bf   = (uint16_t*)(ws + 2 * MB);
  uint16_t* vt_bf  = (uint16_t*)(ws + 4 * MB);   // transposed [d][i]
  uint16_t* pk_bf  = (uint16_t*)(ws + 6 * MB);
  uint16_t* pq_bf  = (uint16_t*)(ws + 10 * MB);
  uint16_t* ctx_bf = (uint16_t*)(ws + 14 * MB);
  float*    out_f  = (float*)   (ws + 16 * MB);
  uint16_t* hs_bf  = (uint16_t*)(ws + 20 * MB);
  uint16_t* rel_bf = (uint16_t*)(ws + 22 * MB);
  uint16_t* Wq_bf  = (uint16_t*)(ws + 26 * MB);
  uint16_t* Wk_bf  = (uint16_t*)(ws + 28 * MB);
  uint16_t* Wv_bf  = (uint16_t*)(ws + 30 * MB);
  uint16_t* Wpk_bf = (uint16_t*)(ws + 32 * MB);
  uint16_t* Wpq_bf = (uint16_t*)(ws + 34 * MB);
  uint16_t* Wo_bf  = (uint16_t*)(ws + 36 * MB);  // total 38 MB

  dim3 blk(256);

  Cast8 c8;
  c8.src[0] = hs;  c8.dst[0] = hs_bf;  c8.n[0] = 1024 * 1024;
  c8.src[1] = rel; c8.dst[1] = rel_bf; c8.n[1] = 2048 * 1024;
  c8.src[2] = Wq;  c8.dst[2] = Wq_bf;  c8.n[2] = 1024 * 1024;
  c8.src[3] = Wk;  c8.dst[3] = Wk_bf;  c8.n[3] = 1024 * 1024;
  c8.src[4] = Wv;  c8.dst[4] = Wv_bf;  c8.n[4] = 1024 * 1024;
  c8.src[5] = Wpk; c8.dst[5] = Wpk_bf; c8.n[5] = 1024 * 1024;
  c8.src[6] = Wpq; c8.dst[6] = Wpq_bf; c8.n[6] = 1024 * 1024;
  c8.src[7] = Wo;  c8.dst[7] = Wo_bf;  c8.n[7] = 1024 * 1024;
  cast8_kernel<<<dim3(1024, 8), blk, 0, stream>>>(c8);

  ProjArgs pa;
  pa.A[0] = hs_bf;  pa.A[1] = hs_bf;  pa.A[2] = hs_bf;  pa.A[3] = rel_bf; pa.A[4] = rel_bf;
  pa.W[0] = Wq_bf;  pa.W[1] = Wk_bf;  pa.W[2] = Wv_bf;  pa.W[3] = Wpk_bf; pa.W[4] = Wpq_bf;
  pa.bias[0] = bq;  pa.bias[1] = bk;  pa.bias[2] = bv;  pa.bias[3] = bpk; pa.bias[4] = bpq;
  pa.C[0] = q_bf; pa.C[1] = k_bf; pa.C[2] = vt_bf; pa.C[3] = pk_bf; pa.C[4] = pq_bf;
  pa.trans[0] = 0; pa.trans[1] = 0; pa.trans[2] = 1; pa.trans[3] = 0; pa.trans[4] = 0;
  proj_gemm<<<dim3(448), blk, 0, stream>>>(pa);

  attn_kernel<<<dim3(512), blk, 0, stream>>>(q_bf, k_bf, vt_bf, pk_bf, pq_bf, ctx_bf);

  out_gemm<<<dim3(256), blk, 0, stream>>>(ctx_bf, Wo_bf, bo, out_f);

  ln_kernel<<<dim3(1024), blk, 0, stream>>>(out_f, hs, lng, lnb, (float*)d_out);
}

// Round 13
// 204.259 us; speedup vs baseline: 1.4712x; 1.0194x over previous
//
#include <hip/hip_runtime.h>
#include <stdint.h>

#define HID 1024
#define NSEQ 1024
#define KREL 1024
#define NHEAD 16
#define DHEAD 64

typedef __attribute__((ext_vector_type(8))) short bhalf8;
typedef __attribute__((ext_vector_type(4))) float floatx4;

__device__ inline uint16_t f2bf(float f) {
  union { float f; uint32_t u; } c; c.f = f;
  uint32_t u = c.u;
  return (uint16_t)((u + 0x7fffu + ((u >> 16) & 1u)) >> 16);
}
__device__ inline uint32_t pkbf(float a, float b) {
  union { float f; uint32_t u; } x, y; x.f = a; y.f = b;
#if __has_builtin(__builtin_amdgcn_perm)
  return __builtin_amdgcn_perm(x.u + 0x8000u, y.u + 0x8000u, 0x03020706u);
#else
  return ((x.u + 0x8000u) >> 16) | ((y.u + 0x8000u) & 0xffff0000u);
#endif
}

// ---------------- fused fp32 -> bf16 casts (8 segments) ----------------
struct Cast8 {
  const float* src[8];
  uint16_t* dst[8];
  int n[8];
};
__global__ __launch_bounds__(256) void cast8_kernel(Cast8 c) {
  int seg = blockIdx.y;
  int n = c.n[seg];
  const float* s = c.src[seg];
  uint16_t* d = c.dst[seg];
  for (int idx = (blockIdx.x * 256 + threadIdx.x) * 4; idx < n; idx += 1024 * 256 * 4) {
    float4 v = *(const float4*)(s + idx);
    ushort4 o;
    o.x = f2bf(v.x); o.y = f2bf(v.y); o.z = f2bf(v.z); o.w = f2bf(v.w);
    *(ushort4*)(d + idx) = o;
  }
}

// ---------------- unified projection GEMM (bf16 in): 128x128 tile, BK=32, sync dbuf ----------------
// (R7/R9/R10/R12-measured best.) z==2 (V) writes transposed Vt[d][i].
struct ProjArgs {
  const uint16_t* A[5];
  const uint16_t* W[5];
  const float* bias[5];
  uint16_t* C[5];
  int trans[5];
};
__global__ __launch_bounds__(256) void proj_gemm(ProjArgs pa) {
  __shared__ uint16_t a_s[2][128 * 40];
  __shared__ uint16_t b_s[2][128 * 40];
  int bidx = blockIdx.x;
  int xcd = bidx & 7, idx = bidx >> 3;
  int g = xcd * 7 + (idx >> 3);
  int nt = idx & 7;
  int z, mt;
  if (g < 24) { z = g >> 3; mt = g & 7; }
  else { int g2 = g - 24; z = 3 + (g2 >> 4); mt = g2 & 15; }
  const uint16_t* A = pa.A[z];
  const uint16_t* W = pa.W[z];
  int i0 = mt * 128, n0 = nt * 128;

  int t = threadIdx.x;
  int lane = t & 63, w = t >> 6;
  int fm = lane & 15, kq = lane >> 4;
  int wm = (w >> 1) * 64, wn = (w & 1) * 64;

  int ra = t >> 1, ca = (t & 1) * 16;
  const uint16_t* Ap = A + (size_t)(i0 + ra) * HID + ca;
  const uint16_t* Wp = W + (size_t)(n0 + ra) * HID + ca;

  floatx4 acc[4][4] = {};

  uint4 ua0 = *(const uint4*)(Ap);
  uint4 ua1 = *(const uint4*)(Ap + 8);
  uint4 ub0 = *(const uint4*)(Wp);
  uint4 ub1 = *(const uint4*)(Wp + 8);
  *(uint4*)(&a_s[0][ra * 40 + ca]) = ua0;
  *(uint4*)(&a_s[0][ra * 40 + ca + 8]) = ua1;
  *(uint4*)(&b_s[0][ra * 40 + ca]) = ub0;
  *(uint4*)(&b_s[0][ra * 40 + ca + 8]) = ub1;

  for (int kt = 0; kt < 32; ++kt) {
    __syncthreads();
    int cur = kt & 1;
    if (kt < 31) {
      int ko = (kt + 1) * 32;
      ua0 = *(const uint4*)(Ap + ko);
      ua1 = *(const uint4*)(Ap + ko + 8);
      ub0 = *(const uint4*)(Wp + ko);
      ub1 = *(const uint4*)(Wp + ko + 8);
    }
    const uint16_t* as = &a_s[cur][0];
    const uint16_t* bs = &b_s[cur][0];
    bhalf8 af[4], bf[4];
#pragma unroll
    for (int m2 = 0; m2 < 4; ++m2)
      af[m2] = *(bhalf8*)(as + (wm + m2 * 16 + fm) * 40 + kq * 8);
#pragma unroll
    for (int n2 = 0; n2 < 4; ++n2)
      bf[n2] = *(bhalf8*)(bs + (wn + n2 * 16 + fm) * 40 + kq * 8);
#pragma unroll
    for (int m2 = 0; m2 < 4; ++m2)
#pragma unroll
      for (int n2 = 0; n2 < 4; ++n2)
        acc[m2][n2] = __builtin_amdgcn_mfma_f32_16x16x32_bf16(af[m2], bf[n2], acc[m2][n2], 0, 0, 0);
    if (kt < 31) {
      int nxt = cur ^ 1;
      *(uint4*)(&a_s[nxt][ra * 40 + ca]) = ua0;
      *(uint4*)(&a_s[nxt][ra * 40 + ca + 8]) = ua1;
      *(uint4*)(&b_s[nxt][ra * 40 + ca]) = ub0;
      *(uint4*)(&b_s[nxt][ra * 40 + ca + 8]) = ub1;
    }
  }

  const float* bias = pa.bias[z];
  uint16_t* C = pa.C[z];
  int tr = pa.trans[z];
#pragma unroll
  for (int m2 = 0; m2 < 4; ++m2) {
    int rowb = i0 + wm + m2 * 16 + kq * 4;
#pragma unroll
    for (int n2 = 0; n2 < 4; ++n2) {
      int col = n0 + wn + n2 * 16 + fm;
      float bv = bias[col];
      floatx4 v = acc[m2][n2];
      if (tr) {
        uint2 p = { pkbf(v[0] + bv, v[1] + bv), pkbf(v[2] + bv, v[3] + bv) };
        *(uint2*)(C + (size_t)col * NSEQ + rowb) = p;
      } else {
#pragma unroll
        for (int r = 0; r < 4; ++r)
          C[(size_t)(rowb + r) * HID + col] = f2bf(v[r] + bv);
      }
    }
  }
}

// ---------------- out-proj GEMM: C = ctx(bf16) @ Wo(bf16)^T + bo, fp32 out ----------------
__global__ __launch_bounds__(256) void out_gemm(const uint16_t* __restrict__ Abf,
                                                const uint16_t* __restrict__ W,
                                                const float* __restrict__ bias,
                                                float* __restrict__ C) {
  __shared__ uint16_t a_s[2][64 * 40];
  __shared__ uint16_t b_s[2][64 * 40];
  int bidx = blockIdx.x;
  int i0 = (bidx >> 4) * 64, n0 = (bidx & 15) * 64;
  int t = threadIdx.x;
  int lane = t & 63, w = t >> 6;
  int fm = lane & 15, kq = lane >> 4;
  int wm = (w >> 1) * 32, wn = (w & 1) * 32;
  int ra = t >> 2, ca = (t & 3) * 8;
  const uint16_t* Ap = Abf + (size_t)(i0 + ra) * HID + ca;
  const uint16_t* Wp = W + (size_t)(n0 + ra) * HID + ca;
  floatx4 acc00 = {0,0,0,0}, acc01 = {0,0,0,0}, acc10 = {0,0,0,0}, acc11 = {0,0,0,0};
  uint4 ua = *(const uint4*)(Ap);
  uint4 ub = *(const uint4*)(Wp);
  *(uint4*)(&a_s[0][ra * 40 + ca]) = ua;
  *(uint4*)(&b_s[0][ra * 40 + ca]) = ub;
  for (int kt = 0; kt < 32; ++kt) {
    __syncthreads();
    int cur = kt & 1;
    if (kt < 31) {
      int ko = (kt + 1) * 32;
      ua = *(const uint4*)(Ap + ko);
      ub = *(const uint4*)(Wp + ko);
    }
    const uint16_t* as = &a_s[cur][0];
    const uint16_t* bs = &b_s[cur][0];
    bhalf8 a0 = *(bhalf8*)(as + (wm + fm) * 40 + kq * 8);
    bhalf8 a1 = *(bhalf8*)(as + (wm + 16 + fm) * 40 + kq * 8);
    bhalf8 b0 = *(bhalf8*)(bs + (wn + fm) * 40 + kq * 8);
    bhalf8 b1 = *(bhalf8*)(bs + (wn + 16 + fm) * 40 + kq * 8);
    acc00 = __builtin_amdgcn_mfma_f32_16x16x32_bf16(a0, b0, acc00, 0, 0, 0);
    acc01 = __builtin_amdgcn_mfma_f32_16x16x32_bf16(a0, b1, acc01, 0, 0, 0);
    acc10 = __builtin_amdgcn_mfma_f32_16x16x32_bf16(a1, b0, acc10, 0, 0, 0);
    acc11 = __builtin_amdgcn_mfma_f32_16x16x32_bf16(a1, b1, acc11, 0, 0, 0);
    if (kt < 31) {
      int nxt = cur ^ 1;
      *(uint4*)(&a_s[nxt][ra * 40 + ca]) = ua;
      *(uint4*)(&b_s[nxt][ra * 40 + ca]) = ub;
    }
  }
  int rb0 = kq * 4;
#define EPO(ACC, SM, SN)                                                   \
  {                                                                        \
    int rowb = i0 + wm + (SM)*16 + rb0;                                    \
    int col = n0 + wn + (SN)*16 + fm;                                      \
    float bv_ = bias[col];                                                 \
    _Pragma("unroll")                                                      \
    for (int rr = 0; rr < 4; ++rr)                                         \
      C[(size_t)(rowb + rr) * HID + col] = ACC[rr] + bv_;                  \
  }
  EPO(acc00, 0, 0) EPO(acc01, 0, 1) EPO(acc10, 1, 0) EPO(acc11, 1, 1)
#undef EPO
}

// ---------------- MFMA fused attention: R12 structure + circular sliding-window staging ----------------
// ONLY change vs R12 (63.2 us): PKw/PQw rows stored at physical = global_row & 63;
// steady-state stages 32 new window rows instead of 64 (staging -33%).
// Barriers, softmax, stage-1 MFMA pattern, operand residency: UNCHANGED (known-good).
__global__ __launch_bounds__(256) void attn_kernel(const uint16_t* __restrict__ qg,
                                                   const uint16_t* __restrict__ kg,
                                                   const uint16_t* __restrict__ vtg,
                                                   const uint16_t* __restrict__ pkg,
                                                   const uint16_t* __restrict__ pqg,
                                                   uint16_t* __restrict__ ctx) {
  const float RSCALE = 0.07216878364870323f;  // 1/sqrt(192)
  __shared__ uint16_t Qs[32][72];
  __shared__ uint16_t Ks[32][72];
  __shared__ uint16_t Vt[64][40];
  __shared__ uint16_t PKw[64][72];   // circular: physical row = global_row & 63
  __shared__ uint16_t PQw[64][72];
  __shared__ float C2P[32][68];
  __shared__ float P2C[32][68];
  __shared__ float Sqk[32][36];
  __shared__ uint16_t Pbf[32][40];
  __shared__ float m_sm[32], l_sm[32], al_sm[32];

  int t = threadIdx.x;
  int lane = t & 63, w = t >> 6;
  int fm = lane & 15;
  int kq = lane >> 4;

  int b = blockIdx.x;
  int xcd = b & 7, slot = b >> 3;
  int h = xcd * 2 + (slot & 1);
  int i0 = (slot >> 1) * 32;
  int cb = h * DHEAD;

  {
    int r = t >> 3, chq = (t & 7) * 8;
    *(uint4*)(&Qs[r][chq]) = *(const uint4*)(qg + (size_t)(i0 + r) * HID + cb + chq);
  }
  if (t < 32) { m_sm[t] = -1e30f; l_sm[t] = 0.f; }

  floatx4 opv0 = {0,0,0,0}, opv1 = {0,0,0,0};
  int wn = w * 16;
  int smt = w >> 1, snt = w & 1;
  int i2 = t >> 3, jj = t & 7;

  int pr = t >> 3, pch = (t & 7) * 8;
  int rV = t >> 2, cV = (t & 3) * 8;
  const uint16_t* kb = kg + cb + pch;
  const uint16_t* vb = vtg + (size_t)(cb + rV) * HID + cV;
  const uint16_t* pkb = pkg + cb + pch;
  const uint16_t* pqb = pqg + cb + pch;

  uint4 rk, rv, rpk0, rpk1, rpq0, rpq1;
  {
    int rbase0 = KREL + i0 - 31;            // tile 0 window base (993..1985)
    rk = *(const uint4*)(kb);
    rv = *(const uint4*)(vb);
    int rg0 = rbase0 + pr;                  // in [993, 2016]
    int rg1 = rbase0 + pr + 32; if (rg1 > 2047) rg1 = 2047;  // clamp only stages row 63 (never read at tile 0)
    rpk0 = *(const uint4*)(pkb + (size_t)rg0 * HID);
    rpk1 = *(const uint4*)(pkb + (size_t)rg1 * HID);
    rpq0 = *(const uint4*)(pqb + (size_t)rg0 * HID);
    rpq1 = *(const uint4*)(pqb + (size_t)rg1 * HID);
  }

  for (int jt = 0; jt < NSEQ / 32; ++jt) {
    int rbase = KREL + i0 - jt * 32 - 31;
    __syncthreads();
    // regs -> LDS: K/V full restage; windows: 32 new rows at physical (global & 63)
    {
      int prow = (rbase + pr) & 63;
      *(uint4*)(&Ks[pr][pch]) = rk;
      *(uint4*)(&Vt[rV][cV]) = rv;
      *(uint4*)(&PKw[prow][pch]) = rpk0;
      *(uint4*)(&PQw[prow][pch]) = rpq0;
      if (jt == 0) {  // uniform branch: tile 0 stages the upper 32 rows too
        *(uint4*)(&PKw[(prow + 32) & 63][pch]) = rpk1;
        *(uint4*)(&PQw[(prow + 32) & 63][pch]) = rpq1;
      }
    }
    __syncthreads();

    // prefetch next tile: K/V tiles + only the 32 NEW window rows [rbase-32, rbase-1]
    if (jt + 1 < NSEQ / 32) {
      int j0 = (jt + 1) * 32;
      int rbn = KREL + i0 - j0 - 31;        // >= 1; rbn+pr <= 1984 -> no clamp
      rk = *(const uint4*)(kb + (size_t)(j0 + pr) * HID);
      rv = *(const uint4*)(vb + j0);
      rpk0 = *(const uint4*)(pkb + (size_t)(rbn + pr) * HID);
      rpq0 = *(const uint4*)(pqb + (size_t)(rbn + pr) * HID);
    }

    // ---- stage 1: window GEMMs + Sqk (R12 pattern; B-row address mapped through circular index) ----
    {
      const uint16_t* Asrc = (w < 2) ? &Qs[0][0] : &Ks[0][0];
      const uint16_t* Bsrc = (w < 2) ? &PKw[0][0] : &PQw[0][0];
      float* Cdst = (w < 2) ? &C2P[0][0] : &P2C[0][0];
      int ntb = (w & 1) * 2;
#pragma unroll
      for (int mt = 0; mt < 2; ++mt) {
        bhalf8 a0 = *(bhalf8*)(Asrc + (mt * 16 + fm) * 72 + kq * 8);
        bhalf8 a1 = *(bhalf8*)(Asrc + (mt * 16 + fm) * 72 + kq * 8 + 32);
#pragma unroll
        for (int nt = ntb; nt < ntb + 2; ++nt) {
          int wrow = (rbase + nt * 16 + fm) & 63;   // logical window row -> physical
          bhalf8 b0 = *(bhalf8*)(Bsrc + wrow * 72 + kq * 8);
          bhalf8 b1 = *(bhalf8*)(Bsrc + wrow * 72 + kq * 8 + 32);
          floatx4 acc = {0,0,0,0};
          acc = __builtin_amdgcn_mfma_f32_16x16x32_bf16(a0, b0, acc, 0, 0, 0);
          acc = __builtin_amdgcn_mfma_f32_16x16x32_bf16(a1, b1, acc, 0, 0, 0);
#pragma unroll
          for (int r = 0; r < 4; ++r)
            Cdst[(mt * 16 + kq * 4 + r) * 68 + nt * 16 + fm] = acc[r];
        }
      }
      bhalf8 qa0 = *(bhalf8*)(&Qs[smt * 16 + fm][kq * 8]);
      bhalf8 qa1 = *(bhalf8*)(&Qs[smt * 16 + fm][kq * 8 + 32]);
      bhalf8 kb0 = *(bhalf8*)(&Ks[snt * 16 + fm][kq * 8]);
      bhalf8 kb1 = *(bhalf8*)(&Ks[snt * 16 + fm][kq * 8 + 32]);
      floatx4 sacc = {0,0,0,0};
      sacc = __builtin_amdgcn_mfma_f32_16x16x32_bf16(qa0, kb0, sacc, 0, 0, 0);
      sacc = __builtin_amdgcn_mfma_f32_16x16x32_bf16(qa1, kb1, sacc, 0, 0, 0);
#pragma unroll
      for (int r = 0; r < 4; ++r)
        Sqk[smt * 16 + kq * 4 + r][snt * 16 + fm] = sacc[r];
    }
    __syncthreads();

    // ---- stage 2: gather + combine + online softmax (unchanged) ----
    {
      float sv[4];
#pragma unroll
      for (int q = 0; q < 4; ++q) {
        int j = jj + 8 * q;
        int rr = i2 - j + 31;  // in [0,62]
        sv[q] = (Sqk[i2][j] + C2P[i2][rr] + P2C[j][rr]) * RSCALE;
      }
      float mx = fmaxf(fmaxf(sv[0], sv[1]), fmaxf(sv[2], sv[3]));
      mx = fmaxf(mx, __shfl_xor(mx, 1));
      mx = fmaxf(mx, __shfl_xor(mx, 2));
      mx = fmaxf(mx, __shfl_xor(mx, 4));
      float m_old = m_sm[i2];
      float m_new = fmaxf(m_old, mx);
      float al = __expf(m_old - m_new);
      float ts = 0.f;
#pragma unroll
      for (int q = 0; q < 4; ++q) {
        float e = __expf(sv[q] - m_new);
        Pbf[i2][jj + 8 * q] = f2bf(e);
        ts += e;
      }
      ts += __shfl_xor(ts, 1);
      ts += __shfl_xor(ts, 2);
      ts += __shfl_xor(ts, 4);
      if (jj == 0) { m_sm[i2] = m_new; l_sm[i2] = l_sm[i2] * al + ts; al_sm[i2] = al; }
    }
    __syncthreads();

    // ---- stage 3: PV via MFMA (unchanged) ----
    {
#pragma unroll
      for (int r = 0; r < 4; ++r) {
        opv0[r] *= al_sm[kq * 4 + r];
        opv1[r] *= al_sm[16 + kq * 4 + r];
      }
      bhalf8 vbf = *(bhalf8*)(&Vt[wn + fm][kq * 8]);
      bhalf8 pa0 = *(bhalf8*)(&Pbf[fm][kq * 8]);
      bhalf8 pa1 = *(bhalf8*)(&Pbf[16 + fm][kq * 8]);
      opv0 = __builtin_amdgcn_mfma_f32_16x16x32_bf16(pa0, vbf, opv0, 0, 0, 0);
      opv1 = __builtin_amdgcn_mfma_f32_16x16x32_bf16(pa1, vbf, opv1, 0, 0, 0);
    }
  }

#pragma unroll
  for (int r = 0; r < 4; ++r) {
    int ia = kq * 4 + r, ib = 16 + kq * 4 + r;
    float la = 1.0f / l_sm[ia], lb = 1.0f / l_sm[ib];
    ctx[(size_t)(i0 + ia) * HID + cb + wn + fm] = f2bf(opv0[r] * la);
    ctx[(size_t)(i0 + ib) * HID + cb + wn + fm] = f2bf(opv1[r] * lb);
  }
}

// ---------------- residual + LayerNorm ----------------
__global__ __launch_bounds__(256) void ln_kernel(const float* __restrict__ xin,
                                                 const float* __restrict__ hs,
                                                 const float* __restrict__ g,
                                                 const float* __restrict__ b,
                                                 float* __restrict__ y) {
  int row = blockIdx.x, t = threadIdx.x;
  int c = t * 4;
  float4 a = *(const float4*)(xin + (size_t)row * HID + c);
  float4 hv = *(const float4*)(hs + (size_t)row * HID + c);
  float x0 = a.x + hv.x, x1 = a.y + hv.y, x2 = a.z + hv.z, x3 = a.w + hv.w;
  float s = x0 + x1 + x2 + x3;
  float sq = x0 * x0 + x1 * x1 + x2 * x2 + x3 * x3;
  for (int off = 32; off; off >>= 1) {
    s += __shfl_xor(s, off);
    sq += __shfl_xor(sq, off);
  }
  __shared__ float rs[4], rq[4];
  int w = t >> 6, lane = t & 63;
  if (lane == 0) { rs[w] = s; rq[w] = sq; }
  __syncthreads();
  s = rs[0] + rs[1] + rs[2] + rs[3];
  sq = rq[0] + rq[1] + rq[2] + rq[3];
  float mu = s * (1.0f / HID);
  float var = sq * (1.0f / HID) - mu * mu;
  float rstd = rsqrtf(var + 1e-7f);
  float4 gg = *(const float4*)(g + c);
  float4 bb = *(const float4*)(b + c);
  float4 out;
  out.x = (x0 - mu) * rstd * gg.x + bb.x;
  out.y = (x1 - mu) * rstd * gg.y + bb.y;
  out.z = (x2 - mu) * rstd * gg.z + bb.z;
  out.w = (x3 - mu) * rstd * gg.w + bb.w;
  *(float4*)(y + (size_t)row * HID + c) = out;
}

extern "C" void kernel_launch(void* const* d_in, const int* in_sizes, int n_in,
                              void* d_out, int out_size, void* d_ws, size_t ws_size,
                              hipStream_t stream) {
  const float* hs  = (const float*)d_in[0];
  const float* rel = (const float*)d_in[1];
  const float* Wq  = (const float*)d_in[2];  const float* bq  = (const float*)d_in[3];
  const float* Wk  = (const float*)d_in[4];  const float* bk  = (const float*)d_in[5];
  const float* Wv  = (const float*)d_in[6];  const float* bv  = (const float*)d_in[7];
  const float* Wpk = (const float*)d_in[8];  const float* bpk = (const float*)d_in[9];
  const float* Wpq = (const float*)d_in[10]; const float* bpq = (const float*)d_in[11];
  const float* Wo  = (const float*)d_in[12]; const float* bo  = (const float*)d_in[13];
  const float* lng = (const float*)d_in[14]; const float* lnb = (const float*)d_in[15];

  char* ws = (char*)d_ws;
  const size_t MB = 1024 * 1024;
  uint16_t* q_bf   = (uint16_t*)(ws + 0 * MB);
  uint16_t* k_bf   = (uint16_t*)(ws + 2 * MB);
  uint16_t* vt_bf  = (uint16_t*)(ws + 4 * MB);   // transposed [d][i]
  uint16_t* pk_bf  = (uint16_t*)(ws + 6 * MB);
  uint16_t* pq_bf  = (uint16_t*)(ws + 10 * MB);
  uint16_t* ctx_bf = (uint16_t*)(ws + 14 * MB);
  float*    out_f  = (float*)   (ws + 16 * MB);
  uint16_t* hs_bf  = (uint16_t*)(ws + 20 * MB);
  uint16_t* rel_bf = (uint16_t*)(ws + 22 * MB);
  uint16_t* Wq_bf  = (uint16_t*)(ws + 26 * MB);
  uint16_t* Wk_bf  = (uint16_t*)(ws + 28 * MB);
  uint16_t* Wv_bf  = (uint16_t*)(ws + 30 * MB);
  uint16_t* Wpk_bf = (uint16_t*)(ws + 32 * MB);
  uint16_t* Wpq_bf = (uint16_t*)(ws + 34 * MB);
  uint16_t* Wo_bf  = (uint16_t*)(ws + 36 * MB);  // total 38 MB

  dim3 blk(256);

  Cast8 c8;
  c8.src[0] = hs;  c8.dst[0] = hs_bf;  c8.n[0] = 1024 * 1024;
  c8.src[1] = rel; c8.dst[1] = rel_bf; c8.n[1] = 2048 * 1024;
  c8.src[2] = Wq;  c8.dst[2] = Wq_bf;  c8.n[2] = 1024 * 1024;
  c8.src[3] = Wk;  c8.dst[3] = Wk_bf;  c8.n[3] = 1024 * 1024;
  c8.src[4] = Wv;  c8.dst[4] = Wv_bf;  c8.n[4] = 1024 * 1024;
  c8.src[5] = Wpk; c8.dst[5] = Wpk_bf; c8.n[5] = 1024 * 1024;
  c8.src[6] = Wpq; c8.dst[6] = Wpq_bf; c8.n[6] = 1024 * 1024;
  c8.src[7] = Wo;  c8.dst[7] = Wo_bf;  c8.n[7] = 1024 * 1024;
  cast8_kernel<<<dim3(1024, 8), blk, 0, stream>>>(c8);

  ProjArgs pa;
  pa.A[0] = hs_bf;  pa.A[1] = hs_bf;  pa.A[2] = hs_bf;  pa.A[3] = rel_bf; pa.A[4] = rel_bf;
  pa.W[0] = Wq_bf;  pa.W[1] = Wk_bf;  pa.W[2] = Wv_bf;  pa.W[3] = Wpk_bf; pa.W[4] = Wpq_bf;
  pa.bias[0] = bq;  pa.bias[1] = bk;  pa.bias[2] = bv;  pa.bias[3] = bpk; pa.bias[4] = bpq;
  pa.C[0] = q_bf; pa.C[1] = k_bf; pa.C[2] = vt_bf; pa.C[3] = pk_bf; pa.C[4] = pq_bf;
  pa.trans[0] = 0; pa.trans[1] = 0; pa.trans[2] = 1; pa.trans[3] = 0; pa.trans[4] = 0;
  proj_gemm<<<dim3(448), blk, 0, stream>>>(pa);

  attn_kernel<<<dim3(512), blk, 0, stream>>>(q_bf, k_bf, vt_bf, pk_bf, pq_bf, ctx_bf);

  out_gemm<<<dim3(256), blk, 0, stream>>>(ctx_bf, Wo_bf, bo, out_f);

  ln_kernel<<<dim3(1024), blk, 0, stream>>>(out_f, hs, lng, lnb, (float*)d_out);
}